// Round 8
// baseline (233.289 us; speedup 1.0000x reference)
//
#include <hip/hip_runtime.h>
#include <stdint.h>

typedef int v4i  __attribute__((ext_vector_type(4)));
typedef int v16i __attribute__((ext_vector_type(16)));

#define EPS_F32 1.1920928955078125e-07f   // np.finfo(float32).eps = 2^-23

// ---------------------------------------------------------------------------
// Fused quant kernel: blocks [0,M) do per-token X quant, blocks [M,M+DOUT)
// do per-out-channel W quant.
// ---------------------------------------------------------------------------
__global__ __launch_bounds__(256) void quant_kernel(
    const float* __restrict__ X, const float* __restrict__ W,
    const float* __restrict__ ss,
    int8_t* __restrict__ Xq, float* __restrict__ xs,
    int8_t* __restrict__ Wq, float* __restrict__ ws,
    int DIN, int M)
{
    const int bid = blockIdx.x;
    const int tid = threadIdx.x;
    const bool isX = bid < M;
    const float* row = isX ? X + (size_t)bid * DIN
                           : W + (size_t)(bid - M) * DIN;

    float4 v[4];
    float amax = 0.f;
#pragma unroll
    for (int c = 0; c < 4; ++c) {
        const int k = c * 1024 + tid * 4;
        float4 xv = *(const float4*)(row + k);
        float4 sv = *(const float4*)(ss + k);
        float4 q;
        if (isX) { q.x = xv.x / sv.x; q.y = xv.y / sv.y;
                   q.z = xv.z / sv.z; q.w = xv.w / sv.w; }
        else     { q.x = xv.x * sv.x; q.y = xv.y * sv.y;
                   q.z = xv.z * sv.z; q.w = xv.w * sv.w; }
        v[c] = q;
        amax = fmaxf(amax, fmaxf(fmaxf(fabsf(q.x), fabsf(q.y)),
                                 fmaxf(fabsf(q.z), fabsf(q.w))));
    }
    __shared__ float red[4];
    for (int off = 32; off; off >>= 1) amax = fmaxf(amax, __shfl_xor(amax, off));
    const int lane = tid & 63, w = tid >> 6;
    if (lane == 0) red[w] = amax;
    __syncthreads();
    amax = fmaxf(fmaxf(red[0], red[1]), fmaxf(red[2], red[3]));

    float scale, lo;
    if (isX) { scale = fmaxf(amax, 1e-5f) / 127.0f;      lo = -127.f; }
    else     { scale = fmaxf(amax / 127.5f, EPS_F32);    lo = -128.f; }
    if (tid == 0) { if (isX) xs[bid] = scale; else ws[bid - M] = scale; }

    int* qout = isX ? (int*)(Xq + (size_t)bid * DIN)
                    : (int*)(Wq + (size_t)(bid - M) * DIN);
#pragma unroll
    for (int c = 0; c < 4; ++c) {
        float4 q = v[c];
        int b0 = (int)fminf(fmaxf(rintf(q.x / scale), lo), 127.f);
        int b1 = (int)fminf(fmaxf(rintf(q.y / scale), lo), 127.f);
        int b2 = (int)fminf(fmaxf(rintf(q.z / scale), lo), 127.f);
        int b3 = (int)fminf(fmaxf(rintf(q.w / scale), lo), 127.f);
        qout[c * 256 + tid] = (b0 & 255) | ((b1 & 255) << 8) |
                              ((b2 & 255) << 16) | ((b3 & 255) << 24);
    }
}

// ---------------------------------------------------------------------------
// Persistent 2-tile int8 NT GEMM, 256x256 tiles, BKB=128, 8 waves (2x4),
// 128 KiB dbuf LDS.  Grid = 256 (1 block/CU).
//
// ROUND 8:
//  * mfma_i32_32x32x32_i8 (4404 TOPS ubench vs 3944 for 16x16x64; half the
//    MFMA instruction count).  Wave tile 128x64 = 4 m-frags x 2 n-frags of
//    32x32, K=128 per kt = 4 k-frags.
//    A/B frag: row(col)=lane&31, k=(lane>>5)*16+e  (generalizes verified
//    16x16 mapping).  C/D: col=lane&31, row=(reg&3)+8*(reg>>2)+4*(lane>>5).
//  * ALL 8 stages issued at P0 (was 4@P0+4@P1): last stage is ~3 MFMA
//    phases (~1750cy) before the per-kt vmcnt(0) -> drain is free.
//
// Phases (fragment-level pipeline, reads one phase ahead of use):
//   P0: 8 stages(next tile) + issue bHi reads [4] + MFMA(aLo x bLo) [8]
//   P1: issue aHi reads [8]                      + MFMA(aLo x bHi) [8]
//   P2: MFMA(aHi x bLo) [8]; then vmcnt(0)+s_barrier  (the per-kt sync)
//   P3: issue aLo,bLo(kt+1) reads [12, next buf] + MFMA(aHi x bHi) [8]
// Sync audit: identical to round 7 (passing) — single vmcnt(0)+barrier/kt
// publishes all 8 stages before P3's buf[next] reads; buf[cur] reads are all
// consumed by P0-P2 MFMAs before the barrier; stages write buf[next] only,
// whose readers all ran before the PREVIOUS kt's barrier. vmcnt(0) has no
// counted-N edge cases on last kt / seg boundary.
// LDS swizzle: LDS[r][c16] = global chunk c16 ^ (r&7); staging source
// pre-swizzled (both-sides rule); all frag-row offsets are 0 mod 8 so the
// read XOR term is lane&7 for every fragment.
// ---------------------------------------------------------------------------
#define BM 256
#define BN 256
#define BKB 128

#define MFMA32 __builtin_amdgcn_mfma_i32_32x32x32_i8

__global__ __launch_bounds__(512, 2) void gemm_i8_kernel(
    const int8_t* __restrict__ Xq, const int8_t* __restrict__ Wq,
    const float* __restrict__ xs, const float* __restrict__ ws,
    const float* __restrict__ bias, float* __restrict__ Y,
    int M, int N, int K)
{
    __shared__ __align__(16) int8_t smem[131072];

    const int tid  = threadIdx.x;
    const int lane = tid & 63;
    const int w    = tid >> 6;
    const int wrow = w >> 2, wcol = w & 3;

    // 256 blocks; XCD-aware: each XCD owns an 8x8 rect of the 32x16 tile grid.
    const int bid    = blockIdx.x;
    const int xcd    = bid & 7, idx = bid >> 3;        // idx in [0,32)
    const int bmBase = (xcd >> 1) * 8 + (idx >> 3);    // seg0 bm; seg1 = +4
    const int bn     = (xcd & 1) * 8 + (idx & 7);

    const int srcSwz = ((lane & 7) ^ (lane >> 3)) << 4;  // staging source swizzle

    // fragment read addressing (32x32x32):
    const int cb = lane >> 5;          // k-chunk select (two 16B chunks per K=32)
    const int s7 = lane & 7;           // swizzle XOR term (row&7 for all frags)
    int ck[4];
#pragma unroll
    for (int kf = 0; kf < 4; ++kf) ck[kf] = ((((kf << 1) | cb) ^ s7) << 4);
    const int rA = ((wrow << 7) + (lane & 31)) << 7;   // A row byte base (row*128)
    const int rB = ((wcol << 6) + (lane & 31)) << 7;   // B row byte base

    auto STAGE = [&](const int8_t* gtile, int region, int rowStart) {
        const int8_t* src = gtile +
            (size_t)(rowStart + (w << 3) + (lane >> 3)) * K + srcSwz;
        __builtin_amdgcn_global_load_lds(
            (const __attribute__((address_space(1))) void*)src,
            (__attribute__((address_space(3))) void*)(smem + region + ((rowStart + (w << 3)) << 7)),
            16, 0, 0);
    };

    v16i acc[4][2] = {};
    v4i aLo[2][4], aHi[2][4], bLo[4], bHi[4];

    const int KT = K / BKB;   // 32
    const int8_t* bT0 = Wq + (size_t)bn * BN * K;   // same B panel both segs

    // prologue: stage tile (seg0,kt0) into buf0; initial aLo/bLo reads
    {
        const int8_t* aT0 = Xq + (size_t)bmBase * BM * K;
        STAGE(aT0, 0,     0);   STAGE(aT0, 0,     64);
        STAGE(aT0, 0,     128); STAGE(aT0, 0,     192);
        STAGE(bT0, 32768, 0);   STAGE(bT0, 32768, 64);
        STAGE(bT0, 32768, 128); STAGE(bT0, 32768, 192);
        asm volatile("s_waitcnt vmcnt(0)" ::: "memory");
        __builtin_amdgcn_s_barrier();
#pragma unroll
        for (int mi = 0; mi < 2; ++mi)
#pragma unroll
            for (int kf = 0; kf < 4; ++kf)
                aLo[mi][kf] = *(const v4i*)(smem + rA + mi * 4096 + ck[kf]);
#pragma unroll
        for (int kf = 0; kf < 4; ++kf)
            bLo[kf] = *(const v4i*)(smem + 32768 + rB + ck[kf]);
    }

    for (int seg = 0; seg < 2; ++seg) {
        const int bm = bmBase + seg * 4;
        const int8_t* aT0 = Xq + (size_t)bm * BM * K;

        for (int kt = 0; kt < KT; ++kt) {
            const int Ab  = (kt & 1) * 65536;
            const int Bb  = Ab + 32768;
            const int nAb = ((kt & 1) ^ 1) * 65536;
            const int nBb = nAb + 32768;
            const bool more = (kt + 1 < KT);
            const bool pf   = more || (seg == 0);
            const int8_t* aTn = more ? aT0 + (size_t)(kt + 1) * BKB
                                     : Xq + (size_t)(bmBase + 4) * BM * K;
            const int8_t* bTn = more ? bT0 + (size_t)(kt + 1) * BKB : bT0;

            // ---- P0: ALL 8 stages; issue bHi reads; MFMA (aLo x bLo)
            if (pf) { STAGE(aTn, nAb, 0);   STAGE(aTn, nAb, 64);
                      STAGE(aTn, nAb, 128); STAGE(aTn, nAb, 192);
                      STAGE(bTn, nBb, 0);   STAGE(bTn, nBb, 64);
                      STAGE(bTn, nBb, 128); STAGE(bTn, nBb, 192); }
#pragma unroll
            for (int kf = 0; kf < 4; ++kf)
                bHi[kf] = *(const v4i*)(smem + Bb + rB + 4096 + ck[kf]);
            __builtin_amdgcn_s_setprio(1);
#pragma unroll
            for (int mi = 0; mi < 2; ++mi)
#pragma unroll
                for (int kf = 0; kf < 4; ++kf)
                    acc[mi][0] = MFMA32(aLo[mi][kf], bLo[kf], acc[mi][0], 0, 0, 0);
            __builtin_amdgcn_s_setprio(0);

            // ---- P1: issue aHi reads; MFMA (aLo x bHi)
#pragma unroll
            for (int mi = 0; mi < 2; ++mi)
#pragma unroll
                for (int kf = 0; kf < 4; ++kf)
                    aHi[mi][kf] = *(const v4i*)(smem + Ab + rA + 8192 + mi * 4096 + ck[kf]);
            __builtin_amdgcn_s_setprio(1);
#pragma unroll
            for (int mi = 0; mi < 2; ++mi)
#pragma unroll
                for (int kf = 0; kf < 4; ++kf)
                    acc[mi][1] = MFMA32(aLo[mi][kf], bHi[kf], acc[mi][1], 0, 0, 0);
            __builtin_amdgcn_s_setprio(0);

            // ---- P2: MFMA (aHi x bLo); then the per-kt sync point
            __builtin_amdgcn_s_setprio(1);
#pragma unroll
            for (int mi = 0; mi < 2; ++mi)
#pragma unroll
                for (int kf = 0; kf < 4; ++kf)
                    acc[2 + mi][0] = MFMA32(aHi[mi][kf], bLo[kf], acc[2 + mi][0], 0, 0, 0);
            __builtin_amdgcn_s_setprio(0);
            asm volatile("s_waitcnt vmcnt(0)" ::: "memory");  // all 8 stages landed
            __builtin_amdgcn_s_barrier();

            // ---- P3: issue aLo/bLo(next) reads from buf[next]; MFMA (aHi x bHi)
            if (pf) {
#pragma unroll
                for (int mi = 0; mi < 2; ++mi)
#pragma unroll
                    for (int kf = 0; kf < 4; ++kf)
                        aLo[mi][kf] = *(const v4i*)(smem + nAb + rA + mi * 4096 + ck[kf]);
#pragma unroll
                for (int kf = 0; kf < 4; ++kf)
                    bLo[kf] = *(const v4i*)(smem + nBb + rB + ck[kf]);
            }
            __builtin_amdgcn_s_setprio(1);
#pragma unroll
            for (int mi = 0; mi < 2; ++mi)
#pragma unroll
                for (int kf = 0; kf < 4; ++kf)
                    acc[2 + mi][1] = MFMA32(aHi[mi][kf], bHi[kf], acc[2 + mi][1], 0, 0, 0);
            __builtin_amdgcn_s_setprio(0);
        }

        // ----- epilogue: dequant + bias.
        // C/D 32x32: col=lane&31, row=(reg&3)+8*(reg>>2)+4*(lane>>5)
        {
            float wsv[2], bv[2];
#pragma unroll
            for (int nj = 0; nj < 2; ++nj) {
                const int n = bn * BN + (wcol << 6) + (nj << 5) + (lane & 31);
                wsv[nj] = ws[n];
                bv[nj]  = bias[n];
            }
#pragma unroll
            for (int mi = 0; mi < 4; ++mi) {
#pragma unroll
                for (int r = 0; r < 16; ++r) {
                    const int m = bm * BM + (wrow << 7) + (mi << 5)
                                + (r & 3) + ((r >> 2) << 3) + (cb << 2);
                    const float xsm = xs[m];
                    float* yrow = Y + (size_t)m * N;
#pragma unroll
                    for (int nj = 0; nj < 2; ++nj) {
                        const int n = bn * BN + (wcol << 6) + (nj << 5) + (lane & 31);
                        yrow[n] = (float)acc[mi][nj][r] * xsm * wsv[nj] + bv[nj];
                    }
                }
            }
        }

        if (seg == 0) {
#pragma unroll
            for (int mi = 0; mi < 4; ++mi)
#pragma unroll
                for (int nj = 0; nj < 2; ++nj)
                    acc[mi][nj] = (v16i){0,0,0,0,0,0,0,0,0,0,0,0,0,0,0,0};
        }
    }
}

// ---------------------------------------------------------------------------
extern "C" void kernel_launch(void* const* d_in, const int* in_sizes, int n_in,
                              void* d_out, int out_size, void* d_ws, size_t ws_size,
                              hipStream_t stream) {
    const float* X    = (const float*)d_in[0];
    const float* W    = (const float*)d_in[1];
    const float* bias = (const float*)d_in[2];
    const float* ss   = (const float*)d_in[3];

    const int DIN  = in_sizes[3];              // 4096
    const int DOUT = in_sizes[2];              // 4096
    const int M    = in_sizes[0] / DIN;        // 8192

    int8_t* Xq = (int8_t*)d_ws;
    int8_t* Wq = Xq + (size_t)M * DIN;
    float*  xs = (float*)(Wq + (size_t)DOUT * DIN);
    float*  ws = xs + M;
    float*  Y  = (float*)d_out;

    quant_kernel<<<M + DOUT, 256, 0, stream>>>(X, W, ss, Xq, xs, Wq, ws, DIN, M);
    gemm_i8_kernel<<<(M / BM) * (DOUT / BN) / 2, 512, 0, stream>>>(Xq, Wq, xs, ws, bias, Y, M, DOUT, DIN);
}

// Round 9
// 182.661 us; speedup vs baseline: 1.2772x; 1.2772x over previous
//
#include <hip/hip_runtime.h>
#include <stdint.h>

typedef int v4i __attribute__((ext_vector_type(4)));

#define EPS_F32 1.1920928955078125e-07f   // np.finfo(float32).eps = 2^-23

// ---------------------------------------------------------------------------
// Fused quant kernel: blocks [0,M) do per-token X quant, blocks [M,M+DOUT)
// do per-out-channel W quant.
// ---------------------------------------------------------------------------
__global__ __launch_bounds__(256) void quant_kernel(
    const float* __restrict__ X, const float* __restrict__ W,
    const float* __restrict__ ss,
    int8_t* __restrict__ Xq, float* __restrict__ xs,
    int8_t* __restrict__ Wq, float* __restrict__ ws,
    int DIN, int M)
{
    const int bid = blockIdx.x;
    const int tid = threadIdx.x;
    const bool isX = bid < M;
    const float* row = isX ? X + (size_t)bid * DIN
                           : W + (size_t)(bid - M) * DIN;

    float4 v[4];
    float amax = 0.f;
#pragma unroll
    for (int c = 0; c < 4; ++c) {
        const int k = c * 1024 + tid * 4;
        float4 xv = *(const float4*)(row + k);
        float4 sv = *(const float4*)(ss + k);
        float4 q;
        if (isX) { q.x = xv.x / sv.x; q.y = xv.y / sv.y;
                   q.z = xv.z / sv.z; q.w = xv.w / sv.w; }
        else     { q.x = xv.x * sv.x; q.y = xv.y * sv.y;
                   q.z = xv.z * sv.z; q.w = xv.w * sv.w; }
        v[c] = q;
        amax = fmaxf(amax, fmaxf(fmaxf(fabsf(q.x), fabsf(q.y)),
                                 fmaxf(fabsf(q.z), fabsf(q.w))));
    }
    __shared__ float red[4];
    for (int off = 32; off; off >>= 1) amax = fmaxf(amax, __shfl_xor(amax, off));
    const int lane = tid & 63, w = tid >> 6;
    if (lane == 0) red[w] = amax;
    __syncthreads();
    amax = fmaxf(fmaxf(red[0], red[1]), fmaxf(red[2], red[3]));

    float scale, lo;
    if (isX) { scale = fmaxf(amax, 1e-5f) / 127.0f;      lo = -127.f; }
    else     { scale = fmaxf(amax / 127.5f, EPS_F32);    lo = -128.f; }
    if (tid == 0) { if (isX) xs[bid] = scale; else ws[bid - M] = scale; }

    int* qout = isX ? (int*)(Xq + (size_t)bid * DIN)
                    : (int*)(Wq + (size_t)(bid - M) * DIN);
#pragma unroll
    for (int c = 0; c < 4; ++c) {
        float4 q = v[c];
        int b0 = (int)fminf(fmaxf(rintf(q.x / scale), lo), 127.f);
        int b1 = (int)fminf(fmaxf(rintf(q.y / scale), lo), 127.f);
        int b2 = (int)fminf(fmaxf(rintf(q.z / scale), lo), 127.f);
        int b3 = (int)fminf(fmaxf(rintf(q.w / scale), lo), 127.f);
        qout[c * 256 + tid] = (b0 & 255) | ((b1 & 255) << 8) |
                              ((b2 & 255) << 16) | ((b3 & 255) << 24);
    }
}

// ---------------------------------------------------------------------------
// Persistent 2-tile int8 NT GEMM, 256x256 tiles, BKB=128, 8 waves (2x4),
// 128 KiB dbuf LDS, mfma_i32_16x16x64_i8.  Grid = 256 (1 block/CU).
//
// ROUND 9 = round-7 kernel (132us, passing) with ONE change: all 8 stages
// issued at P0 (was 4@P0 + 4@P1).  The per-kt vmcnt(0) at P2-end is now
// ~3 MFMA phases (~1950cy) after the last stage issue (>900cy HBM latency)
// -> drain is free.  WAR-safe: stages write buf[next], whose last readers
// ran before the PREVIOUS kt's barrier.
//
// Phases (fragment-level pipeline, reads one phase ahead of use):
//   P0: 8 stages(next tile) + issue bHi(kt) reads [4]  + MFMA(aLo,bLo)
//   P1: issue aHi(kt) reads [8]                        + MFMA(aLo,bHi)
//   P2: MFMA(aHi,bLo); then THE per-kt sync: vmcnt(0)+s_barrier
//   P3: issue aLo,bLo(kt+1) ds_reads [12] (next buffer) + MFMA(aHi,bHi)
// Sync audit identical to round 7: single vmcnt(0)+barrier per kt publishes
// all 8 stages before P3's buf[next] reads; buf[cur] reads are all consumed
// by P0-P2 MFMAs before the barrier; vmcnt(0) has no counted-N edge cases.
// Seg boundary: seamless (seg0-kt31 stages+reads seg1-kt0); epilogue sits
// between P3(kt31,seg0) and P0(kt0,seg1); seg1-kt0's vmcnt(0) drains stores.
// ---------------------------------------------------------------------------
#define BM 256
#define BN 256
#define BKB 128

#define MFMA __builtin_amdgcn_mfma_i32_16x16x64_i8

__global__ __launch_bounds__(512, 2) void gemm_i8_kernel(
    const int8_t* __restrict__ Xq, const int8_t* __restrict__ Wq,
    const float* __restrict__ xs, const float* __restrict__ ws,
    const float* __restrict__ bias, float* __restrict__ Y,
    int M, int N, int K)
{
    __shared__ __align__(16) int8_t smem[131072];

    const int tid  = threadIdx.x;
    const int lane = tid & 63;
    const int w    = tid >> 6;
    const int wrow = w >> 2, wcol = w & 3;

    // 256 blocks; XCD-aware: each XCD owns an 8x8 rect of the 32x16 tile grid.
    const int bid    = blockIdx.x;
    const int xcd    = bid & 7, idx = bid >> 3;        // idx in [0,32)
    const int bmBase = (xcd >> 1) * 8 + (idx >> 3);    // seg0 bm; seg1 = +4
    const int bn     = (xcd & 1) * 8 + (idx & 7);

    const int srcSwz = ((lane & 7) ^ (lane >> 3)) << 4;  // staging source swizzle
    const int chnk0  = ((lane >> 4) ^ (lane & 7)) << 4;  // frag read, k-slice 0
    const int chnk1  = chnk0 ^ 64;                       // k-slice 1
    const int aRB = ((wrow << 6) + (lane & 15)) << 7;    // A frag row-byte base
    const int bRB = ((wcol << 5) + (lane & 15)) << 7;    // B frag row-byte base

    auto STAGE = [&](const int8_t* gtile, int region, int rowStart) {
        const int8_t* src = gtile +
            (size_t)(rowStart + (w << 3) + (lane >> 3)) * K + srcSwz;
        __builtin_amdgcn_global_load_lds(
            (const __attribute__((address_space(1))) void*)src,
            (__attribute__((address_space(3))) void*)(smem + region + ((rowStart + (w << 3)) << 7)),
            16, 0, 0);
    };

    v4i acc[8][4] = {};
    v4i aLo[4][2], aHi[4][2], bLo[2][2], bHi[2][2];

    const int KT = K / BKB;   // 32
    const int8_t* bT0 = Wq + (size_t)bn * BN * K;   // same B panel both segs
    const int rowb = (lane >> 4) << 2;
    const int col  = lane & 15;

    // prologue: stage tile (seg0,kt0) into buf0; initial aLo/bLo reads
    {
        const int8_t* aT0 = Xq + (size_t)bmBase * BM * K;
        STAGE(aT0, 0,     0);   STAGE(aT0, 0,     64);
        STAGE(aT0, 0,     128); STAGE(aT0, 0,     192);
        STAGE(bT0, 32768, 0);   STAGE(bT0, 32768, 64);
        STAGE(bT0, 32768, 128); STAGE(bT0, 32768, 192);
        asm volatile("s_waitcnt vmcnt(0)" ::: "memory");
        __builtin_amdgcn_s_barrier();
#pragma unroll
        for (int i = 0; i < 4; ++i) {
            aLo[i][0] = *(const v4i*)(smem + aRB + i * 2048 + chnk0);
            aLo[i][1] = *(const v4i*)(smem + aRB + i * 2048 + chnk1);
        }
#pragma unroll
        for (int j = 0; j < 2; ++j) {
            bLo[j][0] = *(const v4i*)(smem + 32768 + bRB + j * 2048 + chnk0);
            bLo[j][1] = *(const v4i*)(smem + 32768 + bRB + j * 2048 + chnk1);
        }
    }

    for (int seg = 0; seg < 2; ++seg) {
        const int bm = bmBase + seg * 4;
        const int8_t* aT0 = Xq + (size_t)bm * BM * K;

        for (int kt = 0; kt < KT; ++kt) {
            const int Ab  = (kt & 1) * 65536;
            const int Bb  = Ab + 32768;
            const int nAb = ((kt & 1) ^ 1) * 65536;
            const int nBb = nAb + 32768;
            // next-tile pointers: next kt of this seg, or seg1's kt0
            const bool more = (kt + 1 < KT);
            const bool pf   = more || (seg == 0);
            const int8_t* aTn = more ? aT0 + (size_t)(kt + 1) * BKB
                                     : Xq + (size_t)(bmBase + 4) * BM * K;
            const int8_t* bTn = more ? bT0 + (size_t)(kt + 1) * BKB : bT0;

            // ---- P0: ALL 8 stages; issue bHi reads; MFMA (lo,lo)
            if (pf) { STAGE(aTn, nAb, 0);   STAGE(aTn, nAb, 64);
                      STAGE(aTn, nAb, 128); STAGE(aTn, nAb, 192);
                      STAGE(bTn, nBb, 0);   STAGE(bTn, nBb, 64);
                      STAGE(bTn, nBb, 128); STAGE(bTn, nBb, 192); }
#pragma unroll
            for (int j = 0; j < 2; ++j) {
                bHi[j][0] = *(const v4i*)(smem + Bb + bRB + 16384 + j * 2048 + chnk0);
                bHi[j][1] = *(const v4i*)(smem + Bb + bRB + 16384 + j * 2048 + chnk1);
            }
            __builtin_amdgcn_s_setprio(1);
#pragma unroll
            for (int i = 0; i < 4; ++i)
#pragma unroll
                for (int j = 0; j < 2; ++j) {
                    acc[i][j] = MFMA(aLo[i][0], bLo[j][0], acc[i][j], 0, 0, 0);
                    acc[i][j] = MFMA(aLo[i][1], bLo[j][1], acc[i][j], 0, 0, 0);
                }
            __builtin_amdgcn_s_setprio(0);

            // ---- P1: issue aHi reads; MFMA (lo,hi)
#pragma unroll
            for (int i = 0; i < 4; ++i) {
                aHi[i][0] = *(const v4i*)(smem + Ab + aRB + 16384 + i * 2048 + chnk0);
                aHi[i][1] = *(const v4i*)(smem + Ab + aRB + 16384 + i * 2048 + chnk1);
            }
            __builtin_amdgcn_s_setprio(1);
#pragma unroll
            for (int i = 0; i < 4; ++i)
#pragma unroll
                for (int j = 0; j < 2; ++j) {
                    acc[i][2 + j] = MFMA(aLo[i][0], bHi[j][0], acc[i][2 + j], 0, 0, 0);
                    acc[i][2 + j] = MFMA(aLo[i][1], bHi[j][1], acc[i][2 + j], 0, 0, 0);
                }
            __builtin_amdgcn_s_setprio(0);

            // ---- P2: MFMA (hi,lo); then the per-kt sync point
            __builtin_amdgcn_s_setprio(1);
#pragma unroll
            for (int i = 0; i < 4; ++i)
#pragma unroll
                for (int j = 0; j < 2; ++j) {
                    acc[4 + i][j] = MFMA(aHi[i][0], bLo[j][0], acc[4 + i][j], 0, 0, 0);
                    acc[4 + i][j] = MFMA(aHi[i][1], bLo[j][1], acc[4 + i][j], 0, 0, 0);
                }
            __builtin_amdgcn_s_setprio(0);
            asm volatile("s_waitcnt vmcnt(0)" ::: "memory");  // all 8 stages landed
            __builtin_amdgcn_s_barrier();

            // ---- P3: issue aLo/bLo(next) reads from buf[next]; MFMA (hi,hi)
            if (pf) {
#pragma unroll
                for (int i = 0; i < 4; ++i) {
                    aLo[i][0] = *(const v4i*)(smem + nAb + aRB + i * 2048 + chnk0);
                    aLo[i][1] = *(const v4i*)(smem + nAb + aRB + i * 2048 + chnk1);
                }
#pragma unroll
                for (int j = 0; j < 2; ++j) {
                    bLo[j][0] = *(const v4i*)(smem + nBb + bRB + j * 2048 + chnk0);
                    bLo[j][1] = *(const v4i*)(smem + nBb + bRB + j * 2048 + chnk1);
                }
            }
            __builtin_amdgcn_s_setprio(1);
#pragma unroll
            for (int i = 0; i < 4; ++i)
#pragma unroll
                for (int j = 0; j < 2; ++j) {
                    acc[4 + i][2 + j] = MFMA(aHi[i][0], bHi[j][0], acc[4 + i][2 + j], 0, 0, 0);
                    acc[4 + i][2 + j] = MFMA(aHi[i][1], bHi[j][1], acc[4 + i][2 + j], 0, 0, 0);
                }
            __builtin_amdgcn_s_setprio(0);
        }

        // ----- epilogue: dequant + bias (layout col=lane&15, row=(lane>>4)*4+reg)
        {
            float wsv[4], bv[4];
#pragma unroll
            for (int j = 0; j < 4; ++j) {
                const int n = bn * BN + ((j >> 1) << 7) + (wcol << 5) + ((j & 1) << 4) + col;
                wsv[j] = ws[n];
                bv[j]  = bias[n];
            }
#pragma unroll
            for (int i = 0; i < 8; ++i) {
                const int mbase = bm * BM + ((i >> 2) << 7) + (wrow << 6) + ((i & 3) << 4) + rowb;
#pragma unroll
                for (int r = 0; r < 4; ++r) {
                    const int m = mbase + r;
                    const float xsm = xs[m];
                    float* yrow = Y + (size_t)m * N;
#pragma unroll
                    for (int j = 0; j < 4; ++j) {
                        const int n = bn * BN + ((j >> 1) << 7) + (wcol << 5) + ((j & 1) << 4) + col;
                        yrow[n] = (float)acc[i][j][r] * xsm * wsv[j] + bv[j];
                    }
                }
            }
        }

        if (seg == 0) {
#pragma unroll
            for (int i = 0; i < 8; ++i)
#pragma unroll
                for (int j = 0; j < 4; ++j)
                    acc[i][j] = (v4i){0, 0, 0, 0};
        }
    }
}

// ---------------------------------------------------------------------------
extern "C" void kernel_launch(void* const* d_in, const int* in_sizes, int n_in,
                              void* d_out, int out_size, void* d_ws, size_t ws_size,
                              hipStream_t stream) {
    const float* X    = (const float*)d_in[0];
    const float* W    = (const float*)d_in[1];
    const float* bias = (const float*)d_in[2];
    const float* ss   = (const float*)d_in[3];

    const int DIN  = in_sizes[3];              // 4096
    const int DOUT = in_sizes[2];              // 4096
    const int M    = in_sizes[0] / DIN;        // 8192

    int8_t* Xq = (int8_t*)d_ws;
    int8_t* Wq = Xq + (size_t)M * DIN;
    float*  xs = (float*)(Wq + (size_t)DOUT * DIN);
    float*  ws = xs + M;
    float*  Y  = (float*)d_out;

    quant_kernel<<<M + DOUT, 256, 0, stream>>>(X, W, ss, Xq, xs, Wq, ws, DIN, M);
    gemm_i8_kernel<<<(M / BM) * (DOUT / BN) / 2, 512, 0, stream>>>(Xq, Wq, xs, ws, bias, Y, M, DOUT, DIN);
}

// Round 10
// 178.385 us; speedup vs baseline: 1.3078x; 1.0240x over previous
//
#include <hip/hip_runtime.h>
#include <stdint.h>

typedef int v4i __attribute__((ext_vector_type(4)));

#define EPS_F32 1.1920928955078125e-07f   // np.finfo(float32).eps = 2^-23

// ---------------------------------------------------------------------------
// Fused quant kernel: blocks [0,M) do per-token X quant, blocks [M,M+DOUT)
// do per-out-channel W quant.
// ---------------------------------------------------------------------------
__global__ __launch_bounds__(256) void quant_kernel(
    const float* __restrict__ X, const float* __restrict__ W,
    const float* __restrict__ ss,
    int8_t* __restrict__ Xq, float* __restrict__ xs,
    int8_t* __restrict__ Wq, float* __restrict__ ws,
    int DIN, int M)
{
    const int bid = blockIdx.x;
    const int tid = threadIdx.x;
    const bool isX = bid < M;
    const float* row = isX ? X + (size_t)bid * DIN
                           : W + (size_t)(bid - M) * DIN;

    float4 v[4];
    float amax = 0.f;
#pragma unroll
    for (int c = 0; c < 4; ++c) {
        const int k = c * 1024 + tid * 4;
        float4 xv = *(const float4*)(row + k);
        float4 sv = *(const float4*)(ss + k);
        float4 q;
        if (isX) { q.x = xv.x / sv.x; q.y = xv.y / sv.y;
                   q.z = xv.z / sv.z; q.w = xv.w / sv.w; }
        else     { q.x = xv.x * sv.x; q.y = xv.y * sv.y;
                   q.z = xv.z * sv.z; q.w = xv.w * sv.w; }
        v[c] = q;
        amax = fmaxf(amax, fmaxf(fmaxf(fabsf(q.x), fabsf(q.y)),
                                 fmaxf(fabsf(q.z), fabsf(q.w))));
    }
    __shared__ float red[4];
    for (int off = 32; off; off >>= 1) amax = fmaxf(amax, __shfl_xor(amax, off));
    const int lane = tid & 63, w = tid >> 6;
    if (lane == 0) red[w] = amax;
    __syncthreads();
    amax = fmaxf(fmaxf(red[0], red[1]), fmaxf(red[2], red[3]));

    float scale, lo;
    if (isX) { scale = fmaxf(amax, 1e-5f) / 127.0f;      lo = -127.f; }
    else     { scale = fmaxf(amax / 127.5f, EPS_F32);    lo = -128.f; }
    if (tid == 0) { if (isX) xs[bid] = scale; else ws[bid - M] = scale; }

    int* qout = isX ? (int*)(Xq + (size_t)bid * DIN)
                    : (int*)(Wq + (size_t)(bid - M) * DIN);
#pragma unroll
    for (int c = 0; c < 4; ++c) {
        float4 q = v[c];
        int b0 = (int)fminf(fmaxf(rintf(q.x / scale), lo), 127.f);
        int b1 = (int)fminf(fmaxf(rintf(q.y / scale), lo), 127.f);
        int b2 = (int)fminf(fmaxf(rintf(q.z / scale), lo), 127.f);
        int b3 = (int)fminf(fmaxf(rintf(q.w / scale), lo), 127.f);
        qout[c * 256 + tid] = (b0 & 255) | ((b1 & 255) << 8) |
                              ((b2 & 255) << 16) | ((b3 & 255) << 24);
    }
}

// ---------------------------------------------------------------------------
// Persistent 2-tile int8 NT GEMM, 256x256 tiles, BKB=128, 8 waves (2x4),
// 128 KiB dbuf LDS, mfma_i32_16x16x64_i8.  Grid = 256 (1 block/CU).
//
// ROUND 10: K-half sub-step schedule.  Fragments split by K-chunk (fLO =
// chunk0 of all 8 A-frags + 4 B-frags; fHI = chunk1), not by M/N half.
// Per kt128, two balanced sub-steps of {12 ds_reads || 32 independent MFMA}:
//   S0: 8 stages(next tile) + read fHI(cur) + MFMA(fLO)  [K 0..64)
//       -> vmcnt(0) + s_barrier   (THE per-kt sync, same as r7/r9)
//   S1: read fLO(next buf)        + MFMA(fHI)  [K 64..128)
// Each 12-read burst (~1150cy) hides under a 32-MFMA cluster (~1300cy);
// every MFMA is independent (1 per acc tile); read-use distance ~1300cy.
// Sync skeleton byte-identical to r9 (proven): one vmcnt(0)+barrier per kt,
// stages-at-front, same buffer parity (KT even -> seamless seg rollover),
// pf=false tail degenerates cleanly (vmcnt(0) no-op; skip fLO reads).
// Epilogue between segs: its stores drain at seg1-kt0's vmcnt(0).
// ---------------------------------------------------------------------------
#define BM 256
#define BN 256
#define BKB 128

#define MFMA __builtin_amdgcn_mfma_i32_16x16x64_i8

__global__ __launch_bounds__(512, 2) void gemm_i8_kernel(
    const int8_t* __restrict__ Xq, const int8_t* __restrict__ Wq,
    const float* __restrict__ xs, const float* __restrict__ ws,
    const float* __restrict__ bias, float* __restrict__ Y,
    int M, int N, int K)
{
    __shared__ __align__(16) int8_t smem[131072];

    const int tid  = threadIdx.x;
    const int lane = tid & 63;
    const int w    = tid >> 6;
    const int wrow = w >> 2, wcol = w & 3;

    // 256 blocks; XCD-aware: each XCD owns an 8x8 rect of the 32x16 tile grid.
    const int bid    = blockIdx.x;
    const int xcd    = bid & 7, idx = bid >> 3;        // idx in [0,32)
    const int bmBase = (xcd >> 1) * 8 + (idx >> 3);    // seg0 bm; seg1 = +4
    const int bn     = (xcd & 1) * 8 + (idx & 7);

    const int srcSwz = ((lane & 7) ^ (lane >> 3)) << 4;  // staging source swizzle
    const int chnk0  = ((lane >> 4) ^ (lane & 7)) << 4;  // frag read, k-slice 0
    const int chnk1  = chnk0 ^ 64;                       // k-slice 1
    const int aRB = ((wrow << 6) + (lane & 15)) << 7;    // A frag row-byte base
    const int bRB = ((wcol << 5) + (lane & 15)) << 7;    // B frag row-byte base

    auto STAGE = [&](const int8_t* gtile, int region, int rowStart) {
        const int8_t* src = gtile +
            (size_t)(rowStart + (w << 3) + (lane >> 3)) * K + srcSwz;
        __builtin_amdgcn_global_load_lds(
            (const __attribute__((address_space(1))) void*)src,
            (__attribute__((address_space(3))) void*)(smem + region + ((rowStart + (w << 3)) << 7)),
            16, 0, 0);
    };

    v4i acc[8][4] = {};
    v4i fLA[8], fHA[8], fLB[4], fHB[4];   // K-half fragment sets (static names)

    const int KT = K / BKB;   // 32
    const int8_t* bT0 = Wq + (size_t)bn * BN * K;   // same B panel both segs
    const int rowb = (lane >> 4) << 2;
    const int col  = lane & 15;

    // prologue: stage tile (seg0,kt0) into buf0; read fLO from buf0
    {
        const int8_t* aT0 = Xq + (size_t)bmBase * BM * K;
        STAGE(aT0, 0,     0);   STAGE(aT0, 0,     64);
        STAGE(aT0, 0,     128); STAGE(aT0, 0,     192);
        STAGE(bT0, 32768, 0);   STAGE(bT0, 32768, 64);
        STAGE(bT0, 32768, 128); STAGE(bT0, 32768, 192);
        asm volatile("s_waitcnt vmcnt(0)" ::: "memory");
        __builtin_amdgcn_s_barrier();
#pragma unroll
        for (int i = 0; i < 4; ++i) {
            fLA[i]     = *(const v4i*)(smem + aRB + i * 2048 + chnk0);
            fLA[4 + i] = *(const v4i*)(smem + aRB + 16384 + i * 2048 + chnk0);
        }
#pragma unroll
        for (int j = 0; j < 2; ++j) {
            fLB[j]     = *(const v4i*)(smem + 32768 + bRB + j * 2048 + chnk0);
            fLB[2 + j] = *(const v4i*)(smem + 32768 + bRB + 16384 + j * 2048 + chnk0);
        }
    }

    for (int seg = 0; seg < 2; ++seg) {
        const int bm = bmBase + seg * 4;
        const int8_t* aT0 = Xq + (size_t)bm * BM * K;

        for (int kt = 0; kt < KT; ++kt) {
            const int Ab  = (kt & 1) * 65536;
            const int Bb  = Ab + 32768;
            const int nAb = ((kt & 1) ^ 1) * 65536;
            const int nBb = nAb + 32768;
            const bool more = (kt + 1 < KT);
            const bool pf   = more || (seg == 0);
            const int8_t* aTn = more ? aT0 + (size_t)(kt + 1) * BKB
                                     : Xq + (size_t)(bmBase + 4) * BM * K;
            const int8_t* bTn = more ? bT0 + (size_t)(kt + 1) * BKB : bT0;

            // ---- S0: 8 stages; read fHI(cur); MFMA on fLO (K 0..64)
            if (pf) { STAGE(aTn, nAb, 0);   STAGE(aTn, nAb, 64);
                      STAGE(aTn, nAb, 128); STAGE(aTn, nAb, 192);
                      STAGE(bTn, nBb, 0);   STAGE(bTn, nBb, 64);
                      STAGE(bTn, nBb, 128); STAGE(bTn, nBb, 192); }
#pragma unroll
            for (int i = 0; i < 4; ++i) {
                fHA[i]     = *(const v4i*)(smem + Ab + aRB + i * 2048 + chnk1);
                fHA[4 + i] = *(const v4i*)(smem + Ab + aRB + 16384 + i * 2048 + chnk1);
            }
#pragma unroll
            for (int j = 0; j < 2; ++j) {
                fHB[j]     = *(const v4i*)(smem + Bb + bRB + j * 2048 + chnk1);
                fHB[2 + j] = *(const v4i*)(smem + Bb + bRB + 16384 + j * 2048 + chnk1);
            }
            __builtin_amdgcn_s_setprio(1);
#pragma unroll
            for (int i = 0; i < 8; ++i)
#pragma unroll
                for (int j = 0; j < 4; ++j)
                    acc[i][j] = MFMA(fLA[i], fLB[j], acc[i][j], 0, 0, 0);
            __builtin_amdgcn_s_setprio(0);
            asm volatile("s_waitcnt vmcnt(0)" ::: "memory");  // all 8 stages landed
            __builtin_amdgcn_s_barrier();

            // ---- S1: read fLO(next buf); MFMA on fHI (K 64..128)
            if (pf) {
#pragma unroll
                for (int i = 0; i < 4; ++i) {
                    fLA[i]     = *(const v4i*)(smem + nAb + aRB + i * 2048 + chnk0);
                    fLA[4 + i] = *(const v4i*)(smem + nAb + aRB + 16384 + i * 2048 + chnk0);
                }
#pragma unroll
                for (int j = 0; j < 2; ++j) {
                    fLB[j]     = *(const v4i*)(smem + nBb + bRB + j * 2048 + chnk0);
                    fLB[2 + j] = *(const v4i*)(smem + nBb + bRB + 16384 + j * 2048 + chnk0);
                }
            }
            __builtin_amdgcn_s_setprio(1);
#pragma unroll
            for (int i = 0; i < 8; ++i)
#pragma unroll
                for (int j = 0; j < 4; ++j)
                    acc[i][j] = MFMA(fHA[i], fHB[j], acc[i][j], 0, 0, 0);
            __builtin_amdgcn_s_setprio(0);
        }

        // ----- epilogue: dequant + bias (layout col=lane&15, row=(lane>>4)*4+reg)
        {
            float wsv[4], bv[4];
#pragma unroll
            for (int j = 0; j < 4; ++j) {
                const int n = bn * BN + ((j >> 1) << 7) + (wcol << 5) + ((j & 1) << 4) + col;
                wsv[j] = ws[n];
                bv[j]  = bias[n];
            }
#pragma unroll
            for (int i = 0; i < 8; ++i) {
                const int mbase = bm * BM + ((i >> 2) << 7) + (wrow << 6) + ((i & 3) << 4) + rowb;
#pragma unroll
                for (int r = 0; r < 4; ++r) {
                    const int m = mbase + r;
                    const float xsm = xs[m];
                    float* yrow = Y + (size_t)m * N;
#pragma unroll
                    for (int j = 0; j < 4; ++j) {
                        const int n = bn * BN + ((j >> 1) << 7) + (wcol << 5) + ((j & 1) << 4) + col;
                        yrow[n] = (float)acc[i][j][r] * xsm * wsv[j] + bv[j];
                    }
                }
            }
        }

        if (seg == 0) {
#pragma unroll
            for (int i = 0; i < 8; ++i)
#pragma unroll
                for (int j = 0; j < 4; ++j)
                    acc[i][j] = (v4i){0, 0, 0, 0};
        }
    }
}

// ---------------------------------------------------------------------------
extern "C" void kernel_launch(void* const* d_in, const int* in_sizes, int n_in,
                              void* d_out, int out_size, void* d_ws, size_t ws_size,
                              hipStream_t stream) {
    const float* X    = (const float*)d_in[0];
    const float* W    = (const float*)d_in[1];
    const float* bias = (const float*)d_in[2];
    const float* ss   = (const float*)d_in[3];

    const int DIN  = in_sizes[3];              // 4096
    const int DOUT = in_sizes[2];              // 4096
    const int M    = in_sizes[0] / DIN;        // 8192

    int8_t* Xq = (int8_t*)d_ws;
    int8_t* Wq = Xq + (size_t)M * DIN;
    float*  xs = (float*)(Wq + (size_t)DOUT * DIN);
    float*  ws = xs + M;
    float*  Y  = (float*)d_out;

    quant_kernel<<<M + DOUT, 256, 0, stream>>>(X, W, ss, Xq, xs, Wq, ws, DIN, M);
    gemm_i8_kernel<<<(M / BM) * (DOUT / BN) / 2, 512, 0, stream>>>(Xq, Wq, xs, ws, bias, Y, M, DOUT, DIN);
}